// Round 14
// baseline (579.017 us; speedup 1.0000x reference)
//
#include <hip/hip_runtime.h>

#define NN 10000
#define EE 640000
#define NT64 (EE / 64)   // 10000 tiles of 64 edges

typedef __attribute__((ext_vector_type(8))) short bf16x8;
typedef __attribute__((ext_vector_type(4))) float f32x4;
typedef __attribute__((ext_vector_type(2))) unsigned uint2v;
typedef __attribute__((ext_vector_type(2))) float float2v;

// RTNE (prepass)
__device__ __forceinline__ unsigned f2bf(float f) {
  union { float f; unsigned u; } v; v.f = f;
  return (v.u + 0x7fffu + ((v.u >> 16) & 1u)) >> 16;
}
// fast biased-round (hot loops): <=1 ulp
__device__ __forceinline__ unsigned f2bf_fast(float f) {
  union { float f; unsigned u; } v; v.f = f;
  return (v.u + 0x8000u) >> 16;
}
__device__ __forceinline__ float bf_lo(unsigned u) {
  union { unsigned x; float f; } p; p.x = u << 16; return p.f;
}
__device__ __forceinline__ float bf_hi(unsigned u) {
  union { unsigned x; float f; } p; p.x = u & 0xffff0000u; return p.f;
}
// fast silu: rcp instead of IEEE divide
__device__ __forceinline__ float silu_f(float x) {
  return x * __builtin_amdgcn_rcpf(1.0f + __expf(-x));
}
__device__ __forceinline__ f32x4 mfma16(bf16x8 a, bf16x8 b, f32x4 c) {
  return __builtin_amdgcn_mfma_f32_16x16x32_bf16(a, b, c, 0, 0, 0);
}
// stored position 32w+2a+t holds actual column 32w+16t+a
__device__ __forceinline__ int pi_perm(int k) {
  return (k & ~31) + ((k & 1) << 4) + ((k & 31) >> 1);
}

// ---------------------------------------------------------------------------
// Fused prepass: blocks [0,2500) h->bf16 cvt + edge histogram; [2500,2628)
// weight cvt+transpose (pi-permuted rows on 2nd-layer weights).
// ---------------------------------------------------------------------------
__global__ void k_pre(const float* __restrict__ h, unsigned* __restrict__ h_bf,
                      const int* __restrict__ ei, int* __restrict__ offs,
                      const float* __restrict__ We1, const float* __restrict__ We2,
                      const float* __restrict__ Wc1, const float* __restrict__ Wn1,
                      const float* __restrict__ Wn2,
                      unsigned short* __restrict__ We1t, unsigned short* __restrict__ We2t,
                      unsigned short* __restrict__ Wc1t, unsigned short* __restrict__ Wn1t,
                      unsigned short* __restrict__ Wn2t) {
  const int bid = blockIdx.x;
  if (bid < 2500) {
    const int i = bid * 256 + threadIdx.x;       // < 640000
    const float2 v = ((const float2*)h)[i];
    h_bf[i] = f2bf(v.x) | (f2bf(v.y) << 16);
    atomicAdd(&offs[ei[i] + 1], 1);
  } else {
    const int n = bid - 2500;                    // 0..127
    const int k = threadIdx.x;                   // 0..255
    We1t[n * 256 + k] = (unsigned short)f2bf(We1[k * 128 + n]);
    const int kk = (k < 128) ? k : 128 + pi_perm(k - 128);
    Wn1t[n * 256 + k] = (unsigned short)f2bf(Wn1[kk * 128 + n]);
    if (k < 128) {
      const int pk = pi_perm(k);
      We2t[n * 128 + k] = (unsigned short)f2bf(We2[pk * 128 + n]);
      Wc1t[n * 128 + k] = (unsigned short)f2bf(Wc1[pk * 128 + n]);
      Wn2t[n * 128 + k] = (unsigned short)f2bf(Wn2[pk * 128 + n]);
    }
  }
}

// single block, 1024 threads, 10 elems/thread; 2 barriers total
__global__ void k_scan(int* __restrict__ offs) {
  __shared__ int wsum[16];
  const int tid  = threadIdx.x;
  const int lane = tid & 63;
  const int wv   = tid >> 6;
  const int base = tid * 10;
  int v[10]; int s = 0;
  #pragma unroll
  for (int j = 0; j < 10; ++j) {
    const int i = base + j;
    const int x = (i <= NN) ? offs[i] : 0;
    s += x; v[j] = s;
  }
  int sc = s;
  #pragma unroll
  for (int d = 1; d < 64; d <<= 1) {
    const int t = __shfl_up(sc, d, 64);
    if (lane >= d) sc += t;
  }
  if (lane == 63) wsum[wv] = sc;
  __syncthreads();
  if (wv == 0 && lane < 16) {
    int ws = wsum[lane];
    #pragma unroll
    for (int d = 1; d < 16; d <<= 1) {
      const int t = __shfl_up(ws, d, 64);
      if (lane >= d) ws += t;
    }
    wsum[lane] = ws;
  }
  __syncthreads();
  const int wbase = (wv == 0) ? 0 : wsum[wv - 1];
  const int ebase = wbase + sc - s;
  #pragma unroll
  for (int j = 0; j < 10; ++j) {
    const int i = base + j;
    if (i <= NN) offs[i] = ebase + v[j];
  }
}

__global__ void k_scatter(const int* __restrict__ ei, const float* __restrict__ y,
                          const int* __restrict__ offs, int* __restrict__ cur,
                          unsigned* __restrict__ rcbuf, uint2v* __restrict__ diffpk) {
  const int e = blockIdx.x * 256 + threadIdx.x;
  if (e < EE) {
    const int r = ei[e];
    const int c = ei[EE + e];
    const int pos = offs[r] + atomicAdd(&cur[r], 1);
    rcbuf[pos] = (unsigned)r | ((unsigned)c << 16);
    const float dx = y[r * 3 + 0] - y[c * 3 + 0];
    const float dy = y[r * 3 + 1] - y[c * 3 + 1];
    const float dz = y[r * 3 + 2] - y[c * 3 + 2];
    const float rad = dx * dx + dy * dy + dz * dz;
    uint2v dp;
    dp.x = f2bf(dx) | (f2bf(dy) << 16);
    dp.y = f2bf(dz) | (f2bf(rad) << 16);
    diffpk[pos] = dp;
  }
}

// ---------------------------------------------------------------------------
// Edge kernel: r12 structure + cross-tile REGISTER PREFETCH (rcp after stage
// barrier, dependent gathers after l1 barrier). __launch_bounds__(256,1):
// prefetch adds ~40 VGPRs; the (256,2) 128-cap would spill (r6/r9/r10 lesson:
// spills here cost ~500MB each way — verify FETCH/WRITE stay ~16MB).
// ---------------------------------------------------------------------------
__global__ __launch_bounds__(256, 1)
void egcl_edge8(const unsigned short* __restrict__ h_bf,
                const unsigned* __restrict__ rcbuf, uint2v* __restrict__ diffpk,
                const unsigned short* __restrict__ We1t, const float* __restrict__ We1_last,
                const float* __restrict__ be1,
                const unsigned short* __restrict__ We2t, const float* __restrict__ be2,
                const unsigned short* __restrict__ Wc1t, const float* __restrict__ bc1,
                const float* __restrict__ Wc2,
                int* __restrict__ cnt_g, int* __restrict__ ids_g,
                float2v* __restrict__ pay, float* __restrict__ ovf)
{
  const int tid  = threadIdx.x;
  const int wave = tid >> 6;
  const int lane = tid & 63;
  const int l16  = lane & 15;
  const int quad = lane >> 4;
  const int n0   = wave * 32;

  __shared__ short A_lds[64 * 264];    // 33.8 KB; m2 overlays (A dead then)
  __shared__ short m1_lds[64 * 136];   // 17.4 KB; gsum overlays (m1 dead then)
  __shared__ float rad_lds[64];
  __shared__ float spart[4][64];
  __shared__ short grp_lds[64] __attribute__((aligned(16)));
  __shared__ int   nodeg_lds[64];
  __shared__ int   ngroups_s;
  short* m2_lds = A_lds;
  float* gsum   = (float*)m1_lds;      // 8 x 128 fp32 = 4 KB

  bf16x8 wWe1[8][2], wWe2[4][2], wWc1[4][2];
  float w1last[2], b1v[2], b2v[2], bc1v[2], wc2v[2];
  #pragma unroll
  for (int t = 0; t < 2; ++t) {
    const int n = n0 + t * 16 + l16;
    #pragma unroll
    for (int kc = 0; kc < 8; ++kc)
      wWe1[kc][t] = *(const bf16x8*)(We1t + n * 256 + kc * 32 + quad * 8);
    #pragma unroll
    for (int kc = 0; kc < 4; ++kc) {
      wWe2[kc][t] = *(const bf16x8*)(We2t + n * 128 + kc * 32 + quad * 8);
      wWc1[kc][t] = *(const bf16x8*)(Wc1t + n * 128 + kc * 32 + quad * 8);
    }
    w1last[t] = We1_last[n];
    b1v[t] = be1[n]; b2v[t] = be2[n]; bc1v[t] = bc1[n]; wc2v[t] = Wc2[n];
  }

  const int e_sub = tid >> 4;   // 0..15
  const int s16   = tid & 15;

  // ---- prefetch prologue for first tile ----
  bf16x8 p_a[4], p_b[4];
  uint2v p_dp; p_dp.x = 0; p_dp.y = 0;
  unsigned p_rn = 0;
  {
    const int t0 = blockIdx.x;
    unsigned rcp0[4];
    #pragma unroll
    for (int i = 0; i < 4; ++i) rcp0[i] = rcbuf[t0 * 64 + i * 16 + e_sub];
    #pragma unroll
    for (int i = 0; i < 4; ++i) {
      const int r = rcp0[i] & 0xffffu, c = rcp0[i] >> 16;
      p_a[i] = *(const bf16x8*)(h_bf + (size_t)r * 128 + s16 * 8);
      p_b[i] = *(const bf16x8*)(h_bf + (size_t)c * 128 + s16 * 8);
    }
    if (tid < 64) {
      p_dp = __builtin_nontemporal_load(&diffpk[t0 * 64 + tid]);
      p_rn = rcbuf[t0 * 64 + tid];
    }
  }

  for (int tile = blockIdx.x; tile < NT64; tile += gridDim.x) {
    const int ntile = tile + (int)gridDim.x;
    const int pt = (ntile < NT64) ? ntile : tile;   // clamped (safe, data unused)

    // ---- stage A from prefetched regs + group scan (wave 0) ----
    #pragma unroll
    for (int i = 0; i < 4; ++i) {
      const int m = i * 16 + e_sub;
      *(bf16x8*)(&A_lds[m * 264 + s16 * 8])       = p_a[i];
      *(bf16x8*)(&A_lds[m * 264 + 128 + s16 * 8]) = p_b[i];
    }
    float d0 = 0.f, d1 = 0.f, d2 = 0.f;
    if (tid < 64) {   // wave 0: lane == tid
      d0 = bf_lo(p_dp.x); d1 = bf_hi(p_dp.x); d2 = bf_lo(p_dp.y);
      rad_lds[tid] = bf_hi(p_dp.y);
      const int rn = (int)(p_rn & 0xffffu);
      const int prev = __shfl_up(rn, 1, 64);
      const int b = (tid == 0) ? 0 : (rn != prev ? 1 : 0);
      int g = b;
      #pragma unroll
      for (int d = 1; d < 64; d <<= 1) {
        const int t = __shfl_up(g, d, 64);
        if (tid >= d) g += t;
      }
      grp_lds[tid] = (short)g;
      if (b || tid == 0) nodeg_lds[g] = rn;
      if (tid == 63) ngroups_s = g + 1;
    }
    __syncthreads();
    const int ng = ngroups_s;

    // ---- prefetch stage 1: next tile's rcp words (independent loads) ----
    unsigned n_rcp[4];
    #pragma unroll
    for (int i = 0; i < 4; ++i) n_rcp[i] = rcbuf[pt * 64 + i * 16 + e_sub];
    unsigned n_rn = 0;
    if (tid < 64) n_rn = rcbuf[pt * 64 + tid];

    // ---- layer 1: K=256 ----
    #pragma unroll 2
    for (int si = 0; si < 4; ++si) {
      f32x4 a0 = {0,0,0,0}, a1 = {0,0,0,0};
      #pragma unroll
      for (int kc = 0; kc < 8; ++kc) {
        bf16x8 aA = *(const bf16x8*)(&A_lds[(si * 16 + l16) * 264 + kc * 32 + quad * 8]);
        a0 = mfma16(aA, wWe1[kc][0], a0);
        a1 = mfma16(aA, wWe1[kc][1], a1);
      }
      #pragma unroll
      for (int r = 0; r < 4; ++r) {
        const int m = si * 16 + quad * 4 + r;
        const float rad = rad_lds[m];
        const float v0 = a0[r] + rad * w1last[0] + b1v[0];
        const float v1 = a1[r] + rad * w1last[1] + b1v[1];
        const unsigned pk = (f2bf_fast(silu_f(v0)) & 0xffffu) | (f2bf_fast(silu_f(v1)) << 16);
        *(unsigned*)(&m1_lds[m * 136 + n0 + 2 * l16]) = pk;   // pi-packed
      }
    }
    __syncthreads();   // A_lds dead; m2 overlay may write

    // ---- prefetch stage 2: dependent gathers (rcp arrived during l1) ----
    #pragma unroll
    for (int i = 0; i < 4; ++i) {
      const int r = n_rcp[i] & 0xffffu, c = n_rcp[i] >> 16;
      p_a[i] = *(const bf16x8*)(h_bf + (size_t)r * 128 + s16 * 8);
      p_b[i] = *(const bf16x8*)(h_bf + (size_t)c * 128 + s16 * 8);
    }
    uint2v n_dp; n_dp.x = 0; n_dp.y = 0;
    if (tid < 64) n_dp = __builtin_nontemporal_load(&diffpk[pt * 64 + tid]);

    // ---- layer 2: K=128 -> edge_feat (m2 = A_lds overlay, pi-packed) ----
    #pragma unroll 2
    for (int si = 0; si < 4; ++si) {
      f32x4 a0 = {0,0,0,0}, a1 = {0,0,0,0};
      #pragma unroll
      for (int kc = 0; kc < 4; ++kc) {
        bf16x8 aA = *(const bf16x8*)(&m1_lds[(si * 16 + l16) * 136 + kc * 32 + quad * 8]);
        a0 = mfma16(aA, wWe2[kc][0], a0);
        a1 = mfma16(aA, wWe2[kc][1], a1);
      }
      #pragma unroll
      for (int r = 0; r < 4; ++r) {
        const int m = si * 16 + quad * 4 + r;
        const unsigned pk = (f2bf_fast(silu_f(a0[r] + b2v[0])) & 0xffffu) |
                            (f2bf_fast(silu_f(a1[r] + b2v[1])) << 16);
        *(unsigned*)(&m2_lds[m * 136 + n0 + 2 * l16]) = pk;
      }
    }
    __syncthreads();   // m1 dead from here; gsum overlay may write

    // ---- per-tile group sums: D[g][col] via indicator-MFMA ----
    {
      bf16x8 bf0[2], bf1[2];
      #pragma unroll
      for (int ks = 0; ks < 2; ++ks) {
        #pragma unroll
        for (int j = 0; j < 8; ++j) {
          const int k = ks * 32 + quad * 8 + j;
          bf0[ks][j] = m2_lds[k * 136 + n0 + l16];
          bf1[ks][j] = m2_lds[k * 136 + n0 + 16 + l16];
        }
      }
      for (int si = 0; si < 4 && si * 16 < ng; ++si) {
        f32x4 r0 = {0,0,0,0}, r1 = {0,0,0,0};
        #pragma unroll
        for (int ks = 0; ks < 2; ++ks) {
          const bf16x8 gvec = *(const bf16x8*)(grp_lds + ks * 32 + quad * 8);
          bf16x8 ifrag;
          const short tgt = (short)(si * 16 + l16);
          #pragma unroll
          for (int j = 0; j < 8; ++j)
            ifrag[j] = (gvec[j] == tgt) ? (short)0x3F80 : (short)0;
          r0 = mfma16(ifrag, bf0[ks], r0);
          r1 = mfma16(ifrag, bf1[ks], r1);
        }
        #pragma unroll
        for (int r = 0; r < 4; ++r) {
          const int g = si * 16 + quad * 4 + r;
          if (g < ng) {
            if (g < 8) {
              gsum[g * 128 + n0 + l16]      = r0[r];
              gsum[g * 128 + n0 + 16 + l16] = r1[r];
            } else {   // rare overflow -> zeroed atomic buffer
              const int node = nodeg_lds[g];
              atomicAdd(&ovf[(size_t)node * 128 + n0 + l16],      r0[r]);
              atomicAdd(&ovf[(size_t)node * 128 + n0 + 16 + l16], r1[r]);
            }
          }
        }
      }
      if (wave == 0) {
        if (tid < 8 && tid < ng) ids_g[tile * 8 + tid] = nodeg_lds[tid];
        if (tid == 0) cnt_g[tile] = (ng < 8) ? ng : 8;
      }
    }

    // ---- layer 3: K=128 -> per-edge coord scalar ----
    #pragma unroll 2
    for (int si = 0; si < 4; ++si) {
      f32x4 a0 = {0,0,0,0}, a1 = {0,0,0,0};
      #pragma unroll
      for (int kc = 0; kc < 4; ++kc) {
        bf16x8 aA = *(const bf16x8*)(&m2_lds[(si * 16 + l16) * 136 + kc * 32 + quad * 8]);
        a0 = mfma16(aA, wWc1[kc][0], a0);
        a1 = mfma16(aA, wWc1[kc][1], a1);
      }
      float p[4];
      #pragma unroll
      for (int r = 0; r < 4; ++r) {
        const float c0 = silu_f(a0[r] + bc1v[0]);
        const float c1 = silu_f(a1[r] + bc1v[1]);
        p[r] = c0 * wc2v[0] + c1 * wc2v[1];
      }
      #pragma unroll
      for (int msk = 8; msk >= 1; msk >>= 1) {
        #pragma unroll
        for (int r = 0; r < 4; ++r) p[r] += __shfl_xor(p[r], msk, 64);
      }
      if (l16 == 0) {
        #pragma unroll
        for (int r = 0; r < 4; ++r) spart[wave][si * 16 + quad * 4 + r] = p[r];
      }
    }
    __syncthreads();   // gsum complete; m2/grp consumed; spart ready

    // ---- record payload write: block-private slots, nt ----
    {
      const int nrec = (ng < 8) ? ng : 8;
      for (int g = wave; g < nrec; g += 4) {
        float2v p;
        p.x = gsum[g * 128 + 2 * lane];
        p.y = gsum[g * 128 + 2 * lane + 1];
        __builtin_nontemporal_store(p, &pay[((size_t)tile * 8 + g) * 64 + lane]);
      }
    }

    // ---- tail: per-edge trans write (in-place over diffpk), nt ----
    if (tid < 64) {
      const float s = spart[0][tid] + spart[1][tid] + spart[2][tid] + spart[3][tid];
      uint2v tv;
      tv.x = f2bf_fast(d0 * s) | (f2bf_fast(d1 * s) << 16);
      tv.y = f2bf_fast(d2 * s);
      __builtin_nontemporal_store(tv, &diffpk[tile * 64 + tid]);
    }

    // commit prefetch for next iteration
    p_dp = n_dp;
    p_rn = n_rn;
  }
}

// ---------------------------------------------------------------------------
// Node kernel: gather per-node partial records (~2 tiles/node) + ovf; trans
// CSR reduction for y_out; node MLP. (identical to r12)
// ---------------------------------------------------------------------------
__global__ __launch_bounds__(256, 2)
void egcl_node6(const unsigned short* __restrict__ h_bf, const float* __restrict__ h,
                const float* __restrict__ y,
                const unsigned short* __restrict__ Wn1t, const float* __restrict__ bn1,
                const unsigned short* __restrict__ Wn2t, const float* __restrict__ bn2,
                const int* __restrict__ offs,
                const int* __restrict__ cnt_g, const int* __restrict__ ids_g,
                const float2v* __restrict__ pay, const float* __restrict__ ovf,
                const uint2v* __restrict__ transpk,
                float* __restrict__ h_out, float* __restrict__ y_out)
{
  const int tid  = threadIdx.x;
  const int wave = tid >> 6;
  const int lane = tid & 63;
  const int l16  = lane & 15;
  const int quad = lane >> 4;
  const int n0   = wave * 32;

  __shared__ short A_lds[16 * 264];
  __shared__ short m1_lds[16 * 136];

  bf16x8 wWn1[8][2], wWn2[4][2];
  float bn1v[2], bn2v[2];
  #pragma unroll
  for (int t = 0; t < 2; ++t) {
    const int n = n0 + t * 16 + l16;
    #pragma unroll
    for (int kc = 0; kc < 8; ++kc)
      wWn1[kc][t] = *(const bf16x8*)(Wn1t + n * 256 + kc * 32 + quad * 8);
    #pragma unroll
    for (int kc = 0; kc < 4; ++kc)
      wWn2[kc][t] = *(const bf16x8*)(Wn2t + n * 128 + kc * 32 + quad * 8);
    bn1v[t] = bn1[n]; bn2v[t] = bn2[n];
  }

  const int node0 = blockIdx.x * 16;
  const int e_sub = tid >> 4;
  const int s16   = tid & 15;

  // stage h half (bf16 direct)
  {
    const int nd = node0 + e_sub;
    *(bf16x8*)(&A_lds[e_sub * 264 + s16 * 8]) =
        *(const bf16x8*)(h_bf + (size_t)nd * 128 + s16 * 8);
  }

  // partial-record gather + trans reduction: wave w handles nodes w*4..w*4+3
  #pragma unroll
  for (int i = 0; i < 4; ++i) {
    const int lcl = wave * 4 + i;
    const int nd  = node0 + lcl;
    const int start = offs[nd], end = offs[nd + 1];

    const float2v ov = *(const float2v*)(ovf + (size_t)nd * 128 + 2 * lane);
    float a0 = ov.x, a1 = ov.y;
    if (end > start) {
      const int tA = start >> 6, tB = (end - 1) >> 6;
      for (int t = tA; t <= tB; ++t) {
        const int c = cnt_g[t];
        int g = -1;
        for (int j = 0; j < c; ++j)
          if (ids_g[t * 8 + j] == nd) { g = j; break; }
        if (g >= 0) {
          const float2v p = __builtin_nontemporal_load(&pay[((size_t)t * 8 + g) * 64 + lane]);
          a0 += p.x; a1 += p.y;
        }
      }
    }
    const unsigned pk = (f2bf_fast(a0) & 0xffffu) | (f2bf_fast(a1) << 16);
    *(unsigned*)(&A_lds[lcl * 264 + 128 + lane * 2]) = pk;   // stored (pi) space

    float tx = 0.f, ty = 0.f, tz = 0.f;
    for (int e2 = start + lane; e2 < end; e2 += 64) {
      const uint2v up = __builtin_nontemporal_load(&transpk[e2]);
      tx += bf_lo(up.x); ty += bf_hi(up.x); tz += bf_lo(up.y);
    }
    #pragma unroll
    for (int msk = 32; msk >= 1; msk >>= 1) {
      tx += __shfl_xor(tx, msk, 64);
      ty += __shfl_xor(ty, msk, 64);
      tz += __shfl_xor(tz, msk, 64);
    }
    if (lane < 3) {
      const float inv = 1.0f / fmaxf((float)(end - start), 1.0f);
      const float comp = (lane == 0) ? tx : (lane == 1) ? ty : tz;
      y_out[nd * 3 + lane] = y[nd * 3 + lane] + comp * inv;
    }
  }
  __syncthreads();

  // layer 1: K=256 (rows 128.. of Wn1t pi-permuted to match stored layout)
  {
    f32x4 a00 = {0,0,0,0}, a01 = {0,0,0,0}, a10 = {0,0,0,0}, a11 = {0,0,0,0};
    #pragma unroll
    for (int kc = 0; kc < 8; kc += 2) {
      bf16x8 aA = *(const bf16x8*)(&A_lds[l16 * 264 + kc * 32 + quad * 8]);
      bf16x8 aB = *(const bf16x8*)(&A_lds[l16 * 264 + (kc + 1) * 32 + quad * 8]);
      a00 = mfma16(aA, wWn1[kc][0], a00);
      a10 = mfma16(aA, wWn1[kc][1], a10);
      a01 = mfma16(aB, wWn1[kc + 1][0], a01);
      a11 = mfma16(aB, wWn1[kc + 1][1], a11);
    }
    #pragma unroll
    for (int r = 0; r < 4; ++r) {
      const int m = quad * 4 + r;
      const float v0 = silu_f(a00[r] + a01[r] + bn1v[0]);
      const float v1 = silu_f(a10[r] + a11[r] + bn1v[1]);
      const unsigned pk = (f2bf_fast(v0) & 0xffffu) | (f2bf_fast(v1) << 16);
      *(unsigned*)(&m1_lds[m * 136 + n0 + 2 * l16]) = pk;   // pi-packed
    }
  }
  __syncthreads();

  // layer 2: K=128 (Wn2t pi-permuted) + residual
  {
    f32x4 a00 = {0,0,0,0}, a01 = {0,0,0,0}, a10 = {0,0,0,0}, a11 = {0,0,0,0};
    #pragma unroll
    for (int kc = 0; kc < 4; kc += 2) {
      bf16x8 aA = *(const bf16x8*)(&m1_lds[l16 * 136 + kc * 32 + quad * 8]);
      bf16x8 aB = *(const bf16x8*)(&m1_lds[l16 * 136 + (kc + 1) * 32 + quad * 8]);
      a00 = mfma16(aA, wWn2[kc][0], a00);
      a10 = mfma16(aA, wWn2[kc][1], a10);
      a01 = mfma16(aB, wWn2[kc + 1][0], a01);
      a11 = mfma16(aB, wWn2[kc + 1][1], a11);
    }
    #pragma unroll
    for (int r = 0; r < 4; ++r) {
      const int m = quad * 4 + r;
      const int nd = node0 + m;
      const int na = n0 + l16;
      const int nb = n0 + 16 + l16;
      h_out[(size_t)nd * 128 + na] = h[(size_t)nd * 128 + na] + a00[r] + a01[r] + bn2v[0];
      h_out[(size_t)nd * 128 + nb] = h[(size_t)nd * 128 + nb] + a10[r] + a11[r] + bn2v[1];
    }
  }
}

extern "C" void kernel_launch(void* const* d_in, const int* in_sizes, int n_in,
                              void* d_out, int out_size, void* d_ws, size_t ws_size,
                              hipStream_t stream) {
  (void)in_sizes; (void)n_in; (void)out_size;
  const float* h   = (const float*)d_in[0];
  const float* y   = (const float*)d_in[1];
  const int*   ei  = (const int*)d_in[2];
  const float* We1 = (const float*)d_in[3];
  const float* be1 = (const float*)d_in[4];
  const float* We2 = (const float*)d_in[5];
  const float* be2 = (const float*)d_in[6];
  const float* Wc1 = (const float*)d_in[7];
  const float* bc1 = (const float*)d_in[8];
  const float* Wc2 = (const float*)d_in[9];
  const float* Wn1 = (const float*)d_in[10];
  const float* bn1 = (const float*)d_in[11];
  const float* Wn2 = (const float*)d_in[12];
  const float* bn2 = (const float*)d_in[13];
  const float* We1_last = We1 + 256 * 128;

  float* h_out = (float*)d_out;
  float* y_out = h_out + (size_t)NN * 128;

  size_t off = 0;
  auto alloc = [&](size_t bytes) { size_t o = off; off = (off + bytes + 15) & ~(size_t)15; return o; };
  const size_t off_offs = alloc((size_t)(NN + 1) * 4);
  const size_t off_cur  = alloc((size_t)NN * 4);
  const size_t zero_end = off;
  const size_t off_we1t = alloc((size_t)128 * 256 * 2);
  const size_t off_we2t = alloc((size_t)128 * 128 * 2);
  const size_t off_wc1t = alloc((size_t)128 * 128 * 2);
  const size_t off_wn1t = alloc((size_t)128 * 256 * 2);
  const size_t off_wn2t = alloc((size_t)128 * 128 * 2);
  const size_t off_hbf  = alloc((size_t)NN * 128 * 2);
  const size_t off_rc   = alloc((size_t)EE * 4);
  const size_t off_dpk  = alloc((size_t)EE * 8);
  const size_t off_cnt  = alloc((size_t)NT64 * 4);
  const size_t off_ids  = alloc((size_t)NT64 * 8 * 4);
  const size_t off_pay  = alloc((size_t)NT64 * 8 * 512);   // 40.96 MB
  const size_t off_ovf  = alloc((size_t)NN * 128 * 4);     // 5.12 MB, zeroed
  const size_t need = off;                                 // ~62 MB
  if (ws_size < need) return;

  char* w = (char*)d_ws;
  int* offs   = (int*)(w + off_offs);
  int* cur    = (int*)(w + off_cur);
  unsigned short* We1t = (unsigned short*)(w + off_we1t);
  unsigned short* We2t = (unsigned short*)(w + off_we2t);
  unsigned short* Wc1t = (unsigned short*)(w + off_wc1t);
  unsigned short* Wn1t = (unsigned short*)(w + off_wn1t);
  unsigned short* Wn2t = (unsigned short*)(w + off_wn2t);
  unsigned short* hbf  = (unsigned short*)(w + off_hbf);
  unsigned* rcbuf = (unsigned*)(w + off_rc);
  uint2v* diffpk = (uint2v*)(w + off_dpk);
  int* cnt_g = (int*)(w + off_cnt);
  int* ids_g = (int*)(w + off_ids);
  float2v* pay = (float2v*)(w + off_pay);
  float* ovf = (float*)(w + off_ovf);

  hipMemsetAsync(w, 0, zero_end, stream);                        // offs + cur
  hipMemsetAsync(ovf, 0, (size_t)NN * 128 * 4, stream);          // overflow acc
  k_pre<<<2628, 256, 0, stream>>>(h, (unsigned*)hbf, ei, offs,
                                  We1, We2, Wc1, Wn1, Wn2,
                                  We1t, We2t, Wc1t, Wn1t, Wn2t);
  k_scan<<<1, 1024, 0, stream>>>(offs);
  k_scatter<<<(EE + 255) / 256, 256, 0, stream>>>(ei, y, offs, cur, rcbuf, diffpk);
  egcl_edge8<<<2500, 256, 0, stream>>>(hbf, rcbuf, diffpk,
                                       We1t, We1_last, be1, We2t, be2,
                                       Wc1t, bc1, Wc2, cnt_g, ids_g, pay, ovf);
  egcl_node6<<<NN / 16, 256, 0, stream>>>(hbf, h, y, Wn1t, bn1, Wn2t, bn2,
                                          offs, cnt_g, ids_g, pay, ovf, diffpk,
                                          h_out, y_out);
}

// Round 15
// 397.808 us; speedup vs baseline: 1.4555x; 1.4555x over previous
//
#include <hip/hip_runtime.h>

#define NN 10000
#define EE 640000
#define NT64 (EE / 64)   // 10000 tiles of 64 edges

typedef __attribute__((ext_vector_type(8))) short bf16x8;
typedef __attribute__((ext_vector_type(4))) float f32x4;
typedef __attribute__((ext_vector_type(2))) unsigned uint2v;
typedef __attribute__((ext_vector_type(2))) float float2v;

// RTNE (prepass)
__device__ __forceinline__ unsigned f2bf(float f) {
  union { float f; unsigned u; } v; v.f = f;
  return (v.u + 0x7fffu + ((v.u >> 16) & 1u)) >> 16;
}
// fast biased-round (hot loops): <=1 ulp
__device__ __forceinline__ unsigned f2bf_fast(float f) {
  union { float f; unsigned u; } v; v.f = f;
  return (v.u + 0x8000u) >> 16;
}
__device__ __forceinline__ float bf_lo(unsigned u) {
  union { unsigned x; float f; } p; p.x = u << 16; return p.f;
}
__device__ __forceinline__ float bf_hi(unsigned u) {
  union { unsigned x; float f; } p; p.x = u & 0xffff0000u; return p.f;
}
// fast silu: rcp instead of IEEE divide
__device__ __forceinline__ float silu_f(float x) {
  return x * __builtin_amdgcn_rcpf(1.0f + __expf(-x));
}
__device__ __forceinline__ f32x4 mfma16(bf16x8 a, bf16x8 b, f32x4 c) {
  return __builtin_amdgcn_mfma_f32_16x16x32_bf16(a, b, c, 0, 0, 0);
}
// stored position 32w+2a+t holds actual column 32w+16t+a
__device__ __forceinline__ int pi_perm(int k) {
  return (k & ~31) + ((k & 1) << 4) + ((k & 31) >> 1);
}

// ---------------------------------------------------------------------------
// Fused prepass: [0,2500) h->bf16 cvt + edge histogram; [2500,2628) weight
// cvt+transpose (pi rows on 2nd-layer weights); [2628,3878) zero ovf;
// [3878,3888) zero cur. memset launch covers offs only.
// ---------------------------------------------------------------------------
__global__ void k_pre(const float* __restrict__ h, unsigned* __restrict__ h_bf,
                      const int* __restrict__ ei, int* __restrict__ offs,
                      const float* __restrict__ We1, const float* __restrict__ We2,
                      const float* __restrict__ Wc1, const float* __restrict__ Wn1,
                      const float* __restrict__ Wn2,
                      unsigned short* __restrict__ We1t, unsigned short* __restrict__ We2t,
                      unsigned short* __restrict__ Wc1t, unsigned short* __restrict__ Wn1t,
                      unsigned short* __restrict__ Wn2t,
                      float* __restrict__ ovf, int* __restrict__ cur) {
  const int bid = blockIdx.x;
  if (bid < 2500) {
    const int i = bid * 256 + threadIdx.x;       // < 640000
    const float2 v = ((const float2*)h)[i];
    h_bf[i] = f2bf(v.x) | (f2bf(v.y) << 16);
    atomicAdd(&offs[ei[i] + 1], 1);
  } else if (bid < 2628) {
    const int n = bid - 2500;                    // 0..127
    const int k = threadIdx.x;                   // 0..255
    We1t[n * 256 + k] = (unsigned short)f2bf(We1[k * 128 + n]);
    const int kk = (k < 128) ? k : 128 + pi_perm(k - 128);
    Wn1t[n * 256 + k] = (unsigned short)f2bf(Wn1[kk * 128 + n]);
    if (k < 128) {
      const int pk = pi_perm(k);
      We2t[n * 128 + k] = (unsigned short)f2bf(We2[pk * 128 + n]);
      Wc1t[n * 128 + k] = (unsigned short)f2bf(Wc1[pk * 128 + n]);
      Wn2t[n * 128 + k] = (unsigned short)f2bf(Wn2[pk * 128 + n]);
    }
  } else if (bid < 3878) {
    const int idx = (bid - 2628) * 256 + (int)threadIdx.x;   // < 320000 float4
    float4 z; z.x = 0.f; z.y = 0.f; z.z = 0.f; z.w = 0.f;
    ((float4*)ovf)[idx] = z;
  } else {
    const int idx = (bid - 3878) * 256 + (int)threadIdx.x;   // < 2560 (>= NN ints? 10*256=2560)
    if (idx * 4 < NN) ((int4*)cur)[idx] = make_int4(0, 0, 0, 0);
  }
}

// single block, 1024 threads, 10 elems/thread; 2 barriers total
__global__ void k_scan(int* __restrict__ offs) {
  __shared__ int wsum[16];
  const int tid  = threadIdx.x;
  const int lane = tid & 63;
  const int wv   = tid >> 6;
  const int base = tid * 10;
  int v[10]; int s = 0;
  #pragma unroll
  for (int j = 0; j < 10; ++j) {
    const int i = base + j;
    const int x = (i <= NN) ? offs[i] : 0;
    s += x; v[j] = s;
  }
  int sc = s;
  #pragma unroll
  for (int d = 1; d < 64; d <<= 1) {
    const int t = __shfl_up(sc, d, 64);
    if (lane >= d) sc += t;
  }
  if (lane == 63) wsum[wv] = sc;
  __syncthreads();
  if (wv == 0 && lane < 16) {
    int ws = wsum[lane];
    #pragma unroll
    for (int d = 1; d < 16; d <<= 1) {
      const int t = __shfl_up(ws, d, 64);
      if (lane >= d) ws += t;
    }
    wsum[lane] = ws;
  }
  __syncthreads();
  const int wbase = (wv == 0) ? 0 : wsum[wv - 1];
  const int ebase = wbase + sc - s;
  #pragma unroll
  for (int j = 0; j < 10; ++j) {
    const int i = base + j;
    if (i <= NN) offs[i] = ebase + v[j];
  }
}

// scatter only 4B (r|c) per edge — third of r12's scattered bytes
__global__ void k_scatter(const int* __restrict__ ei, const int* __restrict__ offs,
                          int* __restrict__ cur, unsigned* __restrict__ rcbuf) {
  const int e = blockIdx.x * 256 + threadIdx.x;
  if (e < EE) {
    const int r = ei[e];
    const int c = ei[EE + e];
    const int pos = offs[r] + atomicAdd(&cur[r], 1);
    rcbuf[pos] = (unsigned)r | ((unsigned)c << 16);
  }
}

// ---------------------------------------------------------------------------
// Edge kernel: r12 structure; diff/rad computed in-kernel from y (replaces
// diffpk load); trans written to fresh transpk buffer. (256,2): 128-VGPR cap
// — r6/r9/r10 lesson: spilling here costs ~500MB each way; verify F/W ~16MB.
// ---------------------------------------------------------------------------
__global__ __launch_bounds__(256, 2)
void egcl_edge9(const unsigned short* __restrict__ h_bf, const float* __restrict__ y,
                const unsigned* __restrict__ rcbuf,
                const unsigned short* __restrict__ We1t, const float* __restrict__ We1_last,
                const float* __restrict__ be1,
                const unsigned short* __restrict__ We2t, const float* __restrict__ be2,
                const unsigned short* __restrict__ Wc1t, const float* __restrict__ bc1,
                const float* __restrict__ Wc2,
                int* __restrict__ cnt_g, int* __restrict__ ids_g,
                float2v* __restrict__ pay, float* __restrict__ ovf,
                uint2v* __restrict__ transpk)
{
  const int tid  = threadIdx.x;
  const int wave = tid >> 6;
  const int lane = tid & 63;
  const int l16  = lane & 15;
  const int quad = lane >> 4;
  const int n0   = wave * 32;

  __shared__ short A_lds[64 * 264];    // 33.8 KB; m2 overlays (A dead then)
  __shared__ short m1_lds[64 * 136];   // 17.4 KB; gsum overlays (m1 dead then)
  __shared__ float rad_lds[64];
  __shared__ float spart[4][64];
  __shared__ short grp_lds[64] __attribute__((aligned(16)));
  __shared__ int   nodeg_lds[64];
  __shared__ int   ngroups_s;
  short* m2_lds = A_lds;
  float* gsum   = (float*)m1_lds;      // 8 x 128 fp32 = 4 KB

  bf16x8 wWe1[8][2], wWe2[4][2], wWc1[4][2];
  float w1last[2], b1v[2], b2v[2], bc1v[2], wc2v[2];
  #pragma unroll
  for (int t = 0; t < 2; ++t) {
    const int n = n0 + t * 16 + l16;
    #pragma unroll
    for (int kc = 0; kc < 8; ++kc)
      wWe1[kc][t] = *(const bf16x8*)(We1t + n * 256 + kc * 32 + quad * 8);
    #pragma unroll
    for (int kc = 0; kc < 4; ++kc) {
      wWe2[kc][t] = *(const bf16x8*)(We2t + n * 128 + kc * 32 + quad * 8);
      wWc1[kc][t] = *(const bf16x8*)(Wc1t + n * 128 + kc * 32 + quad * 8);
    }
    w1last[t] = We1_last[n];
    b1v[t] = be1[n]; b2v[t] = be2[n]; bc1v[t] = bc1[n]; wc2v[t] = Wc2[n];
  }

  const int e_sub = tid >> 4;   // 0..15
  const int s16   = tid & 15;

  for (int tile = blockIdx.x; tile < NT64; tile += gridDim.x) {
    // ---- stage A + diff/rad from y + group scan (wave 0) ----
    #pragma unroll
    for (int i = 0; i < 4; ++i) {
      const int m = i * 16 + e_sub;
      const unsigned rcp = rcbuf[tile * 64 + m];
      const int r = rcp & 0xffffu;
      const int c = rcp >> 16;
      *(bf16x8*)(&A_lds[m * 264 + s16 * 8]) =
          *(const bf16x8*)(h_bf + (size_t)r * 128 + s16 * 8);
      *(bf16x8*)(&A_lds[m * 264 + 128 + s16 * 8]) =
          *(const bf16x8*)(h_bf + (size_t)c * 128 + s16 * 8);
    }
    float d0 = 0.f, d1 = 0.f, d2 = 0.f;
    if (tid < 64) {   // wave 0: lane == tid
      const unsigned rcp = rcbuf[tile * 64 + tid];
      const int r = rcp & 0xffffu, c = rcp >> 16;
      d0 = y[r * 3 + 0] - y[c * 3 + 0];
      d1 = y[r * 3 + 1] - y[c * 3 + 1];
      d2 = y[r * 3 + 2] - y[c * 3 + 2];
      rad_lds[tid] = d0 * d0 + d1 * d1 + d2 * d2;
      const int rn = r;
      const int prev = __shfl_up(rn, 1, 64);
      const int b = (tid == 0) ? 0 : (rn != prev ? 1 : 0);
      int g = b;
      #pragma unroll
      for (int d = 1; d < 64; d <<= 1) {
        const int t = __shfl_up(g, d, 64);
        if (tid >= d) g += t;
      }
      grp_lds[tid] = (short)g;
      if (b || tid == 0) nodeg_lds[g] = rn;
      if (tid == 63) ngroups_s = g + 1;
    }
    __syncthreads();
    const int ng = ngroups_s;   // register copy: survives later barriers

    // ---- layer 1: K=256 ----
    #pragma unroll 2
    for (int si = 0; si < 4; ++si) {
      f32x4 a0 = {0,0,0,0}, a1 = {0,0,0,0};
      #pragma unroll
      for (int kc = 0; kc < 8; ++kc) {
        bf16x8 aA = *(const bf16x8*)(&A_lds[(si * 16 + l16) * 264 + kc * 32 + quad * 8]);
        a0 = mfma16(aA, wWe1[kc][0], a0);
        a1 = mfma16(aA, wWe1[kc][1], a1);
      }
      #pragma unroll
      for (int r = 0; r < 4; ++r) {
        const int m = si * 16 + quad * 4 + r;
        const float rad = rad_lds[m];
        const float v0 = a0[r] + rad * w1last[0] + b1v[0];
        const float v1 = a1[r] + rad * w1last[1] + b1v[1];
        const unsigned pk = (f2bf_fast(silu_f(v0)) & 0xffffu) | (f2bf_fast(silu_f(v1)) << 16);
        *(unsigned*)(&m1_lds[m * 136 + n0 + 2 * l16]) = pk;   // pi-packed
      }
    }
    __syncthreads();   // A_lds dead; m2 overlay may write

    // ---- layer 2: K=128 -> edge_feat (m2 = A_lds overlay, pi-packed) ----
    #pragma unroll 2
    for (int si = 0; si < 4; ++si) {
      f32x4 a0 = {0,0,0,0}, a1 = {0,0,0,0};
      #pragma unroll
      for (int kc = 0; kc < 4; ++kc) {
        bf16x8 aA = *(const bf16x8*)(&m1_lds[(si * 16 + l16) * 136 + kc * 32 + quad * 8]);
        a0 = mfma16(aA, wWe2[kc][0], a0);
        a1 = mfma16(aA, wWe2[kc][1], a1);
      }
      #pragma unroll
      for (int r = 0; r < 4; ++r) {
        const int m = si * 16 + quad * 4 + r;
        const unsigned pk = (f2bf_fast(silu_f(a0[r] + b2v[0])) & 0xffffu) |
                            (f2bf_fast(silu_f(a1[r] + b2v[1])) << 16);
        *(unsigned*)(&m2_lds[m * 136 + n0 + 2 * l16]) = pk;
      }
    }
    __syncthreads();   // m1 dead from here; gsum overlay may write

    // ---- per-tile group sums: D[g][col] via indicator-MFMA ----
    {
      bf16x8 bf0[2], bf1[2];
      #pragma unroll
      for (int ks = 0; ks < 2; ++ks) {
        #pragma unroll
        for (int j = 0; j < 8; ++j) {
          const int k = ks * 32 + quad * 8 + j;
          bf0[ks][j] = m2_lds[k * 136 + n0 + l16];
          bf1[ks][j] = m2_lds[k * 136 + n0 + 16 + l16];
        }
      }
      for (int si = 0; si < 4 && si * 16 < ng; ++si) {
        f32x4 r0 = {0,0,0,0}, r1 = {0,0,0,0};
        #pragma unroll
        for (int ks = 0; ks < 2; ++ks) {
          const bf16x8 gvec = *(const bf16x8*)(grp_lds + ks * 32 + quad * 8);
          bf16x8 ifrag;
          const short tgt = (short)(si * 16 + l16);
          #pragma unroll
          for (int j = 0; j < 8; ++j)
            ifrag[j] = (gvec[j] == tgt) ? (short)0x3F80 : (short)0;
          r0 = mfma16(ifrag, bf0[ks], r0);
          r1 = mfma16(ifrag, bf1[ks], r1);
        }
        #pragma unroll
        for (int r = 0; r < 4; ++r) {
          const int g = si * 16 + quad * 4 + r;
          if (g < ng) {
            if (g < 8) {
              gsum[g * 128 + n0 + l16]      = r0[r];
              gsum[g * 128 + n0 + 16 + l16] = r1[r];
            } else {   // rare overflow -> zeroed atomic buffer
              const int node = nodeg_lds[g];
              atomicAdd(&ovf[(size_t)node * 128 + n0 + l16],      r0[r]);
              atomicAdd(&ovf[(size_t)node * 128 + n0 + 16 + l16], r1[r]);
            }
          }
        }
      }
      if (wave == 0) {
        if (tid < 8 && tid < ng) ids_g[tile * 8 + tid] = nodeg_lds[tid];
        if (tid == 0) cnt_g[tile] = (ng < 8) ? ng : 8;
      }
    }

    // ---- layer 3: K=128 -> per-edge coord scalar ----
    #pragma unroll 2
    for (int si = 0; si < 4; ++si) {
      f32x4 a0 = {0,0,0,0}, a1 = {0,0,0,0};
      #pragma unroll
      for (int kc = 0; kc < 4; ++kc) {
        bf16x8 aA = *(const bf16x8*)(&m2_lds[(si * 16 + l16) * 136 + kc * 32 + quad * 8]);
        a0 = mfma16(aA, wWc1[kc][0], a0);
        a1 = mfma16(aA, wWc1[kc][1], a1);
      }
      float p[4];
      #pragma unroll
      for (int r = 0; r < 4; ++r) {
        const float c0 = silu_f(a0[r] + bc1v[0]);
        const float c1 = silu_f(a1[r] + bc1v[1]);
        p[r] = c0 * wc2v[0] + c1 * wc2v[1];
      }
      #pragma unroll
      for (int msk = 8; msk >= 1; msk >>= 1) {
        #pragma unroll
        for (int r = 0; r < 4; ++r) p[r] += __shfl_xor(p[r], msk, 64);
      }
      if (l16 == 0) {
        #pragma unroll
        for (int r = 0; r < 4; ++r) spart[wave][si * 16 + quad * 4 + r] = p[r];
      }
    }
    __syncthreads();   // gsum complete; m2/grp consumed; spart ready

    // ---- record payload write: block-private slots, nt ----
    {
      const int nrec = (ng < 8) ? ng : 8;
      for (int g = wave; g < nrec; g += 4) {
        float2v p;
        p.x = gsum[g * 128 + 2 * lane];
        p.y = gsum[g * 128 + 2 * lane + 1];
        __builtin_nontemporal_store(p, &pay[((size_t)tile * 8 + g) * 64 + lane]);
      }
    }

    // ---- tail: per-edge trans write (fresh transpk buffer), nt ----
    if (tid < 64) {
      const float s = spart[0][tid] + spart[1][tid] + spart[2][tid] + spart[3][tid];
      uint2v tv;
      tv.x = f2bf_fast(d0 * s) | (f2bf_fast(d1 * s) << 16);
      tv.y = f2bf_fast(d2 * s);
      __builtin_nontemporal_store(tv, &transpk[tile * 64 + tid]);
    }
  }
}

// ---------------------------------------------------------------------------
// Node kernel: gather per-node partial records (~2 tiles/node) + ovf; trans
// CSR reduction for y_out; node MLP. (identical to r12)
// ---------------------------------------------------------------------------
__global__ __launch_bounds__(256, 2)
void egcl_node6(const unsigned short* __restrict__ h_bf, const float* __restrict__ h,
                const float* __restrict__ y,
                const unsigned short* __restrict__ Wn1t, const float* __restrict__ bn1,
                const unsigned short* __restrict__ Wn2t, const float* __restrict__ bn2,
                const int* __restrict__ offs,
                const int* __restrict__ cnt_g, const int* __restrict__ ids_g,
                const float2v* __restrict__ pay, const float* __restrict__ ovf,
                const uint2v* __restrict__ transpk,
                float* __restrict__ h_out, float* __restrict__ y_out)
{
  const int tid  = threadIdx.x;
  const int wave = tid >> 6;
  const int lane = tid & 63;
  const int l16  = lane & 15;
  const int quad = lane >> 4;
  const int n0   = wave * 32;

  __shared__ short A_lds[16 * 264];
  __shared__ short m1_lds[16 * 136];

  bf16x8 wWn1[8][2], wWn2[4][2];
  float bn1v[2], bn2v[2];
  #pragma unroll
  for (int t = 0; t < 2; ++t) {
    const int n = n0 + t * 16 + l16;
    #pragma unroll
    for (int kc = 0; kc < 8; ++kc)
      wWn1[kc][t] = *(const bf16x8*)(Wn1t + n * 256 + kc * 32 + quad * 8);
    #pragma unroll
    for (int kc = 0; kc < 4; ++kc)
      wWn2[kc][t] = *(const bf16x8*)(Wn2t + n * 128 + kc * 32 + quad * 8);
    bn1v[t] = bn1[n]; bn2v[t] = bn2[n];
  }

  const int node0 = blockIdx.x * 16;
  const int e_sub = tid >> 4;
  const int s16   = tid & 15;

  // stage h half (bf16 direct)
  {
    const int nd = node0 + e_sub;
    *(bf16x8*)(&A_lds[e_sub * 264 + s16 * 8]) =
        *(const bf16x8*)(h_bf + (size_t)nd * 128 + s16 * 8);
  }

  // partial-record gather + trans reduction: wave w handles nodes w*4..w*4+3
  #pragma unroll
  for (int i = 0; i < 4; ++i) {
    const int lcl = wave * 4 + i;
    const int nd  = node0 + lcl;
    const int start = offs[nd], end = offs[nd + 1];

    const float2v ov = *(const float2v*)(ovf + (size_t)nd * 128 + 2 * lane);
    float a0 = ov.x, a1 = ov.y;
    if (end > start) {
      const int tA = start >> 6, tB = (end - 1) >> 6;
      for (int t = tA; t <= tB; ++t) {
        const int c = cnt_g[t];
        int g = -1;
        for (int j = 0; j < c; ++j)
          if (ids_g[t * 8 + j] == nd) { g = j; break; }
        if (g >= 0) {
          const float2v p = __builtin_nontemporal_load(&pay[((size_t)t * 8 + g) * 64 + lane]);
          a0 += p.x; a1 += p.y;
        }
      }
    }
    const unsigned pk = (f2bf_fast(a0) & 0xffffu) | (f2bf_fast(a1) << 16);
    *(unsigned*)(&A_lds[lcl * 264 + 128 + lane * 2]) = pk;   // stored (pi) space

    float tx = 0.f, ty = 0.f, tz = 0.f;
    for (int e2 = start + lane; e2 < end; e2 += 64) {
      const uint2v up = __builtin_nontemporal_load(&transpk[e2]);
      tx += bf_lo(up.x); ty += bf_hi(up.x); tz += bf_lo(up.y);
    }
    #pragma unroll
    for (int msk = 32; msk >= 1; msk >>= 1) {
      tx += __shfl_xor(tx, msk, 64);
      ty += __shfl_xor(ty, msk, 64);
      tz += __shfl_xor(tz, msk, 64);
    }
    if (lane < 3) {
      const float inv = 1.0f / fmaxf((float)(end - start), 1.0f);
      const float comp = (lane == 0) ? tx : (lane == 1) ? ty : tz;
      y_out[nd * 3 + lane] = y[nd * 3 + lane] + comp * inv;
    }
  }
  __syncthreads();

  // layer 1: K=256 (rows 128.. of Wn1t pi-permuted to match stored layout)
  {
    f32x4 a00 = {0,0,0,0}, a01 = {0,0,0,0}, a10 = {0,0,0,0}, a11 = {0,0,0,0};
    #pragma unroll
    for (int kc = 0; kc < 8; kc += 2) {
      bf16x8 aA = *(const bf16x8*)(&A_lds[l16 * 264 + kc * 32 + quad * 8]);
      bf16x8 aB = *(const bf16x8*)(&A_lds[l16 * 264 + (kc + 1) * 32 + quad * 8]);
      a00 = mfma16(aA, wWn1[kc][0], a00);
      a10 = mfma16(aA, wWn1[kc][1], a10);
      a01 = mfma16(aB, wWn1[kc + 1][0], a01);
      a11 = mfma16(aB, wWn1[kc + 1][1], a11);
    }
    #pragma unroll
    for (int r = 0; r < 4; ++r) {
      const int m = quad * 4 + r;
      const float v0 = silu_f(a00[r] + a01[r] + bn1v[0]);
      const float v1 = silu_f(a10[r] + a11[r] + bn1v[1]);
      const unsigned pk = (f2bf_fast(v0) & 0xffffu) | (f2bf_fast(v1) << 16);
      *(unsigned*)(&m1_lds[m * 136 + n0 + 2 * l16]) = pk;   // pi-packed
    }
  }
  __syncthreads();

  // layer 2: K=128 (Wn2t pi-permuted) + residual
  {
    f32x4 a00 = {0,0,0,0}, a01 = {0,0,0,0}, a10 = {0,0,0,0}, a11 = {0,0,0,0};
    #pragma unroll
    for (int kc = 0; kc < 4; kc += 2) {
      bf16x8 aA = *(const bf16x8*)(&m1_lds[l16 * 136 + kc * 32 + quad * 8]);
      bf16x8 aB = *(const bf16x8*)(&m1_lds[l16 * 136 + (kc + 1) * 32 + quad * 8]);
      a00 = mfma16(aA, wWn2[kc][0], a00);
      a10 = mfma16(aA, wWn2[kc][1], a10);
      a01 = mfma16(aB, wWn2[kc + 1][0], a01);
      a11 = mfma16(aB, wWn2[kc + 1][1], a11);
    }
    #pragma unroll
    for (int r = 0; r < 4; ++r) {
      const int m = quad * 4 + r;
      const int nd = node0 + m;
      const int na = n0 + l16;
      const int nb = n0 + 16 + l16;
      h_out[(size_t)nd * 128 + na] = h[(size_t)nd * 128 + na] + a00[r] + a01[r] + bn2v[0];
      h_out[(size_t)nd * 128 + nb] = h[(size_t)nd * 128 + nb] + a10[r] + a11[r] + bn2v[1];
    }
  }
}

extern "C" void kernel_launch(void* const* d_in, const int* in_sizes, int n_in,
                              void* d_out, int out_size, void* d_ws, size_t ws_size,
                              hipStream_t stream) {
  (void)in_sizes; (void)n_in; (void)out_size;
  const float* h   = (const float*)d_in[0];
  const float* y   = (const float*)d_in[1];
  const int*   ei  = (const int*)d_in[2];
  const float* We1 = (const float*)d_in[3];
  const float* be1 = (const float*)d_in[4];
  const float* We2 = (const float*)d_in[5];
  const float* be2 = (const float*)d_in[6];
  const float* Wc1 = (const float*)d_in[7];
  const float* bc1 = (const float*)d_in[8];
  const float* Wc2 = (const float*)d_in[9];
  const float* Wn1 = (const float*)d_in[10];
  const float* bn1 = (const float*)d_in[11];
  const float* Wn2 = (const float*)d_in[12];
  const float* bn2 = (const float*)d_in[13];
  const float* We1_last = We1 + 256 * 128;

  float* h_out = (float*)d_out;
  float* y_out = h_out + (size_t)NN * 128;

  size_t off = 0;
  auto alloc = [&](size_t bytes) { size_t o = off; off = (off + bytes + 15) & ~(size_t)15; return o; };
  const size_t off_offs = alloc((size_t)(NN + 1) * 4);
  const size_t zero_end = off;                             // memset covers offs only
  const size_t off_cur  = alloc((size_t)((NN + 3) / 4) * 16);  // int4-aligned
  const size_t off_we1t = alloc((size_t)128 * 256 * 2);
  const size_t off_we2t = alloc((size_t)128 * 128 * 2);
  const size_t off_wc1t = alloc((size_t)128 * 128 * 2);
  const size_t off_wn1t = alloc((size_t)128 * 256 * 2);
  const size_t off_wn2t = alloc((size_t)128 * 128 * 2);
  const size_t off_hbf  = alloc((size_t)NN * 128 * 2);
  const size_t off_rc   = alloc((size_t)EE * 4);
  const size_t off_tpk  = alloc((size_t)EE * 8);
  const size_t off_cnt  = alloc((size_t)NT64 * 4);
  const size_t off_ids  = alloc((size_t)NT64 * 8 * 4);
  const size_t off_pay  = alloc((size_t)NT64 * 8 * 512);   // 40.96 MB
  const size_t off_ovf  = alloc((size_t)NN * 128 * 4);     // 5.12 MB, zeroed by k_pre
  const size_t need = off;                                 // ~62 MB
  if (ws_size < need) return;

  char* w = (char*)d_ws;
  int* offs   = (int*)(w + off_offs);
  int* cur    = (int*)(w + off_cur);
  unsigned short* We1t = (unsigned short*)(w + off_we1t);
  unsigned short* We2t = (unsigned short*)(w + off_we2t);
  unsigned short* Wc1t = (unsigned short*)(w + off_wc1t);
  unsigned short* Wn1t = (unsigned short*)(w + off_wn1t);
  unsigned short* Wn2t = (unsigned short*)(w + off_wn2t);
  unsigned short* hbf  = (unsigned short*)(w + off_hbf);
  unsigned* rcbuf = (unsigned*)(w + off_rc);
  uint2v* transpk = (uint2v*)(w + off_tpk);
  int* cnt_g = (int*)(w + off_cnt);
  int* ids_g = (int*)(w + off_ids);
  float2v* pay = (float2v*)(w + off_pay);
  float* ovf = (float*)(w + off_ovf);

  hipMemsetAsync(w, 0, zero_end, stream);                        // offs only
  k_pre<<<3888, 256, 0, stream>>>(h, (unsigned*)hbf, ei, offs,
                                  We1, We2, Wc1, Wn1, Wn2,
                                  We1t, We2t, Wc1t, Wn1t, Wn2t, ovf, cur);
  k_scan<<<1, 1024, 0, stream>>>(offs);
  k_scatter<<<(EE + 255) / 256, 256, 0, stream>>>(ei, offs, cur, rcbuf);
  egcl_edge9<<<2500, 256, 0, stream>>>(hbf, y, rcbuf,
                                       We1t, We1_last, be1, We2t, be2,
                                       Wc1t, bc1, Wc2, cnt_g, ids_g, pay, ovf, transpk);
  egcl_node6<<<NN / 16, 256, 0, stream>>>(hbf, h, y, Wn1t, bn1, Wn2t, bn2,
                                          offs, cnt_g, ids_g, pay, ovf, transpk,
                                          h_out, y_out);
}